// Round 7
// baseline (293.892 us; speedup 1.0000x reference)
//
#include <hip/hip_runtime.h>
#include <math.h>

#define NB 10
#define H 512
#define W 512
#define OH 507
#define OW 507
#define TW 32           // output tile width
#define TH 16           // output tile height
#define HC 39           // hist cols (ox0-1 .. ox0+TW+6)
#define HCP 40          // padded row stride -> 160B, 16B-aligned rows
#define HR 23           // hist rows
#define XR 14           // xin rows per phase
#define IC 42           // xin padded stride (41 cols used)

// numpy float32 remainder (np.mod): fmod then sign-fix, each op exact IEEE f32.
__device__ __forceinline__ float f32mod10(float a) {
    float r = fmodf(a, 10.0f);
    if (r < 0.0f) r = __fadd_rn(r, 10.0f);
    return r;
}

__global__ __launch_bounds__(256, 4)
void hog_fused(const float* __restrict__ x, float* __restrict__ out) {
    __shared__ __align__(16) float hist[NB][HR][HCP]; // 9200 f
    __shared__ __align__(16) float xin[XR][IC];       // 588 f; buf0 later
    // total 9788 f = 39,152 B -> 4 blocks/CU

    const int tid = threadIdx.x;
    const int ox0 = blockIdx.x * TW;
    const int oy0 = blockIdx.y * TH;
    const int n   = blockIdx.z;
    const float* __restrict__ xp = x + (size_t)n * (H * W);

    // ---- zero hist (b128) ----
    {
        float4* h4 = (float4*)&hist[0][0][0];         // 9200 = 2300*4
        for (int i = tid; i < 2300; i += 256) h4[i] = make_float4(0.f, 0.f, 0.f, 0.f);
    }

    // ---- two-phase: load xin half-halo, scatter into hist ----
    for (int phse = 0; phse < 2; ++phse) {
        const int hr0   = phse ? 12 : 0;      // hist rows this phase
        const int nrows = phse ? 11 : 12;
        const int ybase = phse ? (oy0 + 10) : (oy0 - 2);
        const int nr    = phse ? 13 : 14;     // xin rows to load
        for (int i = tid; i < nr * 41; i += 256) {
            int r = i / 41, c = i % 41;
            int gy = ybase + r, gx = ox0 - 2 + c;
            float v = 0.0f;
            if ((unsigned)gy < H && (unsigned)gx < W) v = xp[gy * W + gx];
            xin[r][c] = v;
        }
        __syncthreads();

        const int tot = nrows * HC;
        for (int p = tid; p < tot; p += 256) {
            int lr = p / HC, hc = p % HC;     // xin top row = lr in both phases
            int hr = hr0 + lr;
            int hy = oy0 - 1 + hr, hx = ox0 - 1 + hc;
            if ((unsigned)hy >= H || (unsigned)hx >= W) continue; // pool pad: zero
            float a00 = xin[lr][hc],     a01 = xin[lr][hc + 1],     a02 = xin[lr][hc + 2];
            float a10 = xin[lr + 1][hc],                            a12 = xin[lr + 1][hc + 2];
            float a20 = xin[lr + 2][hc], a21 = xin[lr + 2][hc + 1], a22 = xin[lr + 2][hc + 2];

            // exact numpy-order f32 conv (no contraction) — proven in round 3
            float gxv = __fadd_rn(a00, -a02);
            gxv = __fadd_rn(gxv, __fmul_rn(2.0f, a10));
            gxv = __fadd_rn(gxv, -__fmul_rn(2.0f, a12));
            gxv = __fadd_rn(gxv, a20);
            gxv = __fadd_rn(gxv, -a22);
            float gyv = __fadd_rn(a00, __fmul_rn(2.0f, a01));
            gyv = __fadd_rn(gyv, a02);
            gyv = __fadd_rn(gyv, -a20);
            gyv = __fadd_rn(gyv, -__fmul_rn(2.0f, a21));
            gyv = __fadd_rn(gyv, -a22);

            float ay_ = fabsf(gxv), ax_ = fabsf(gyv);
            float hi = fmaxf(ax_, ay_), lo = fminf(ax_, ay_);
            if (hi == 0.0f) continue;         // atan2(0,0)=0 -> contributes 0
            float nrm = __builtin_amdgcn_sqrtf(
                __fadd_rn(__fmul_rn(gxv, gxv), __fmul_rn(gyv, gyv)));

            // fast f32 atan2(gxv, gyv) * 10/pi, divide-free
            bool exact = (hi < 1e-30f) || (hi > 1e30f);
            float pint = 0.0f;
            if (!exact) {
                float t  = lo * __builtin_amdgcn_rcpf(hi);
                bool red = t > 0.41421356f;
                float u  = red ? (t - 1.0f) * __builtin_amdgcn_rcpf(t + 1.0f) : t;
                float z  = u * u;
                float pl = ((8.05374449538e-2f * z - 1.38776856032e-1f) * z
                            + 1.99777106478e-1f) * z - 3.33329491539e-1f;
                float a  = fmaf(u * z, pl, u);
                if (red) a += 0.78539816339744831f;
                if (ay_ > ax_) a = 1.57079632679489662f - a;
                if (gyv < 0.0f) a = 3.14159265358979324f - a;
                float ph = (gxv < 0.0f) ? -a : a;
                pint = ph * 3.18309886183790672f;
                if (fabsf(pint - rintf(pint)) < 1e-4f) exact = true;
            }

            float b_v, t_v;
            int ib, it;
            if (exact) {
                // bit-exact round-3 chain (matches np f32 reference)
                float phf = (float)atan2((double)gxv, (double)gyv);
                float pe  = __fmul_rn(__fdiv_rn(phf, (float)3.14159265358979323846), 10.0f);
                float bfv = floorf(pe), tfv = ceilf(pe);
                float fm = f32mod10(pe), bm = f32mod10(bfv), tm = f32mod10(tfv);
                t_v = __fmul_rn(nrm, __fsub_rn(1.0f, __fsub_rn(tm, fm)));
                b_v = __fmul_rn(nrm, __fsub_rn(1.0f, __fsub_rn(fm, bm)));
                ib = (((int)bfv % NB) + NB) % NB;
                it = (((int)tfv % NB) + NB) % NB;
            } else {
                // pint in (-10,10), >=1e-4 from any integer. Wrap strips
                // (t-index 0, tm=0) occur exactly when ib==9.
                float bfv  = floorf(pint);
                float frac = pint - bfv;
                float fm   = (pint < 0.0f) ? pint + 10.0f : pint;
                b_v = nrm * (1.0f - frac);
                int bi = (int)bfv;
                ib = (bi < 0) ? bi + 10 : bi;
                if (ib == 9) { it = 0;      t_v = nrm * (1.0f + fm); }
                else         { it = ib + 1; t_v = nrm * frac; }
            }
            // single owner per (hr,hc): ds_add_f32, no RMW round-trip
            atomicAdd(&hist[ib][hr][hc], b_v);
            atomicAdd(&hist[it][hr][hc], t_v);
        }
        __syncthreads();
    }

    // ---- vertical 8-row sliding sum, IN PLACE (rows keep 40-f stride) ----
    // colsum(0) -> buf0 (dead xin); colsum(i>=1) -> hist row i-1 (dead).
    float* buf0 = &xin[0][0];                          // 400 f
    for (int q = tid; q < NB * HCP; q += 256) {
        int b = q / HCP, hc = q % HCP;                 // hc=39: pad, stays 0
        float s = 0.0f;
        #pragma unroll
        for (int hr = 0; hr < 8; ++hr) s += hist[b][hr][hc];
        buf0[b * HCP + hc] = s;
        #pragma unroll 4
        for (int i = 1; i < TH; ++i) {
            s += hist[b][i + 7][hc] - hist[b][i - 1][hc];
            hist[b][i - 1][hc] = s;                    // overwrite after last read
        }
    }
    __syncthreads();

    // ---- horizontal 8-col sum via aligned b128 reads + store ----
    // unit u: b = u>>7, i = (u>>3)&15, g = u&7 -> output cols ox0+4g..+3
    float* __restrict__ outn = out + (size_t)n * NB * OH * OW;
    for (int u = tid; u < NB * TH * 8; u += 256) {
        int b = u >> 7;
        int i = (u >> 3) & 15;
        int g = u & 7;
        int oy = oy0 + i;
        if (oy >= OH) continue;
        const float* cs = (i == 0) ? (buf0 + b * HCP) : &hist[b][i - 1][0];
        float4 A = *(const float4*)(cs + 4 * g);       // cols 4g..4g+3
        float4 B = *(const float4*)(cs + 4 * g + 4);   // cols 4g+4..4g+7
        float4 C = *(const float4*)(cs + 4 * g + 8);   // cols 4g+8..4g+11 (col39=0 pad)
        float o0 = ((A.x + A.y) + (A.z + A.w)) + ((B.x + B.y) + (B.z + B.w));
        float o1 = o0 - A.x + C.x;
        float o2 = o1 - A.y + C.y;
        float o3 = o2 - A.z + C.z;
        int oxg = ox0 + 4 * g;
        float* po = outn + (size_t)((unsigned)(b * OH + oy) * OW + oxg);
        if (oxg + 3 < OW) {
            po[0] = o0 * (1.0f / 64.0f);
            po[1] = o1 * (1.0f / 64.0f);
            po[2] = o2 * (1.0f / 64.0f);
            po[3] = o3 * (1.0f / 64.0f);
        } else {
            if (oxg     < OW) po[0] = o0 * (1.0f / 64.0f);
            if (oxg + 1 < OW) po[1] = o1 * (1.0f / 64.0f);
            if (oxg + 2 < OW) po[2] = o2 * (1.0f / 64.0f);
        }
    }
}

extern "C" void kernel_launch(void* const* d_in, const int* in_sizes, int n_in,
                              void* d_out, int out_size, void* d_ws, size_t ws_size,
                              hipStream_t stream) {
    const float* x = (const float*)d_in[0];
    // d_in[1] is the fixed Sobel weight [2,1,3,3]; hard-coded in the kernel.
    float* out = (float*)d_out;
    dim3 grid((OW + TW - 1) / TW, (OH + TH - 1) / TH, 32);
    hog_fused<<<grid, dim3(256), 0, stream>>>(x, out);
}

// Round 8
// 209.020 us; speedup vs baseline: 1.4061x; 1.4061x over previous
//
#include <hip/hip_runtime.h>
#include <math.h>

#define NB 10
#define H 512
#define W 512
#define OH 507
#define OW 507
#define TW 32           // output tile width
#define TH 16           // output tile height
#define HC (TW + 7)     // 39 hist cols  (ox0-1 .. ox0+TW+6)
#define HR (TH + 7)     // 23 hist rows
#define IC (TW + 9)     // 41 input cols (ox0-2 .. ox0+TW+7)
#define IR (TH + 9)     // 25 input rows

// numpy float32 remainder (np.mod): fmod then sign-fix, each op exact IEEE f32.
__device__ __forceinline__ float f32mod10(float a) {
    float r = fmodf(a, 10.0f);
    if (r < 0.0f) r = __fadd_rn(r, 10.0f);
    return r;
}

__global__ __launch_bounds__(256, 4)
void hog_fused(const float* __restrict__ x, float* __restrict__ out) {
    __shared__ __align__(16) float xin[IR][IC];      // 1025 f; reused as buf0 later
    __shared__ __align__(16) float hist[NB][HR][HC]; // 8970 f
    // total 9995 f = 39,980 B -> 4 blocks/CU

    const int tid = threadIdx.x;
    const int ox0 = blockIdx.x * TW;
    const int oy0 = blockIdx.y * TH;
    const int n   = blockIdx.z;
    const float* __restrict__ xp = x + (size_t)n * (H * W);

    // ---- zero hist (vectorized) ----
    float* hflat = &hist[0][0][0];
    {
        float4* h4 = (float4*)hflat;                 // 8970 = 2242*4 + 2
        for (int i = tid; i < 2242; i += 256) h4[i] = make_float4(0.f, 0.f, 0.f, 0.f);
        if (tid < 2) hflat[8968 + tid] = 0.0f;
    }

    // ---- load input tile with halo (zero padded outside image) ----
    float* xflat = &xin[0][0];
    for (int i = tid; i < IR * IC; i += 256) {
        int r = i / IC, c = i % IC;
        int gy = oy0 - 2 + r, gx = ox0 - 2 + c;
        float v = 0.0f;
        if (gy >= 0 && gy < H && gx >= 0 && gx < W) v = xp[gy * W + gx];
        xflat[i] = v;
    }
    __syncthreads();

    // ---- Sobel + phase + 2-bin scatter into LDS hist (round-6 proven) ----
    for (int p = tid; p < HR * HC; p += 256) {
        int hr = p / HC, hc = p % HC;
        int hy = oy0 - 1 + hr, hx = ox0 - 1 + hc;
        if (hy < 0 || hy >= H || hx < 0 || hx >= W) continue;  // pool pad: zero
        float a00 = xin[hr][hc],     a01 = xin[hr][hc + 1],     a02 = xin[hr][hc + 2];
        float a10 = xin[hr + 1][hc],                            a12 = xin[hr + 1][hc + 2];
        float a20 = xin[hr + 2][hc], a21 = xin[hr + 2][hc + 1], a22 = xin[hr + 2][hc + 2];

        // exact numpy-order f32 conv (no contraction) — proven in round 3
        float gxv = __fadd_rn(a00, -a02);
        gxv = __fadd_rn(gxv, __fmul_rn(2.0f, a10));
        gxv = __fadd_rn(gxv, -__fmul_rn(2.0f, a12));
        gxv = __fadd_rn(gxv, a20);
        gxv = __fadd_rn(gxv, -a22);
        float gyv = __fadd_rn(a00, __fmul_rn(2.0f, a01));
        gyv = __fadd_rn(gyv, a02);
        gyv = __fadd_rn(gyv, -a20);
        gyv = __fadd_rn(gyv, -__fmul_rn(2.0f, a21));
        gyv = __fadd_rn(gyv, -a22);

        float ay_ = fabsf(gxv), ax_ = fabsf(gyv);
        float hi = fmaxf(ax_, ay_), lo = fminf(ax_, ay_);
        if (hi == 0.0f) continue;            // atan2(0,0)=0 -> contributes 0
        float nrm = __builtin_amdgcn_sqrtf(
            __fadd_rn(__fmul_rn(gxv, gxv), __fmul_rn(gyv, gyv)));

        // fast f32 atan2(gxv, gyv) * 10/pi, divide-free
        bool exact = (hi < 1e-30f) || (hi > 1e30f);
        float pint = 0.0f;
        if (!exact) {
            float t  = lo * __builtin_amdgcn_rcpf(hi);
            bool red = t > 0.41421356f;
            float u  = red ? (t - 1.0f) * __builtin_amdgcn_rcpf(t + 1.0f) : t;
            float z  = u * u;
            float pl = ((8.05374449538e-2f * z - 1.38776856032e-1f) * z
                        + 1.99777106478e-1f) * z - 3.33329491539e-1f;
            float a  = fmaf(u * z, pl, u);
            if (red) a += 0.78539816339744831f;
            if (ay_ > ax_) a = 1.57079632679489662f - a;
            if (gyv < 0.0f) a = 3.14159265358979324f - a;
            float ph = (gxv < 0.0f) ? -a : a;
            pint = ph * 3.18309886183790672f;
            if (fabsf(pint - rintf(pint)) < 1e-4f) exact = true;
        }

        float b_v, t_v;
        int ib, it;
        if (exact) {
            // bit-exact round-3 chain (matches np f32 reference)
            float phf = (float)atan2((double)gxv, (double)gyv);
            float pe  = __fmul_rn(__fdiv_rn(phf, (float)3.14159265358979323846), 10.0f);
            float bfv = floorf(pe), tfv = ceilf(pe);
            float fm = f32mod10(pe), bm = f32mod10(bfv), tm = f32mod10(tfv);
            t_v = __fmul_rn(nrm, __fsub_rn(1.0f, __fsub_rn(tm, fm)));
            b_v = __fmul_rn(nrm, __fsub_rn(1.0f, __fsub_rn(fm, bm)));
            ib = (((int)bfv % NB) + NB) % NB;
            it = (((int)tfv % NB) + NB) % NB;
        } else {
            // pint in (-10,10), >=1e-4 from any integer. Wrap strips
            // (t-index 0, tm=0) occur exactly when ib==9.
            float bfv  = floorf(pint);
            float frac = pint - bfv;
            float fm   = (pint < 0.0f) ? pint + 10.0f : pint;
            b_v = nrm * (1.0f - frac);
            int bi = (int)bfv;
            ib = (bi < 0) ? bi + 10 : bi;
            if (ib == 9) { it = 0;      t_v = nrm * (1.0f + fm); }
            else         { it = ib + 1; t_v = nrm * frac; }
        }
        // single owner per (hr,hc): plain RMW (LDS atomics are SLOW — round 7)
        hist[ib][hr][hc] = __fadd_rn(hist[ib][hr][hc], b_v);
        hist[it][hr][hc] = __fadd_rn(hist[it][hr][hc], t_v);
    }
    __syncthreads();

    // ---- vertical 8-row sliding sum, IN PLACE (round-6 proven) ----
    float* buf0 = &xin[0][0];                          // [NB][HC] = 390 f
    for (int q = tid; q < NB * HC; q += 256) {
        int b = q / HC, hc = q % HC;
        float s = 0.0f;
        #pragma unroll
        for (int hr = 0; hr < 8; ++hr) s += hist[b][hr][hc];
        buf0[b * HC + hc] = s;
        #pragma unroll 4
        for (int i = 1; i < TH; ++i) {
            s += hist[b][i + 7][hc] - hist[b][i - 1][hc];
            hist[b][i - 1][hc] = s;                    // overwrite after last read
        }
    }
    __syncthreads();

    // ---- horizontal: sliding 8-sum, 4 outputs per unit (11 reads vs 32) ----
    // unit u: b = u>>7, i = (u>>3)&15, g4 = u&7 -> output cols ox0+4*g4 .. +3
    float* __restrict__ outn = out + (size_t)n * (NB * OH * OW);
    for (int u = tid; u < NB * TH * 8; u += 256) {
        int b  = u >> 7;
        int i  = (u >> 3) & 15;
        int g4 = u & 7;
        int oy = oy0 + i;
        if (oy >= OH) continue;
        const float* cs = (i == 0) ? (buf0 + b * HC) : &hist[b][i - 1][0];
        const float* p  = cs + 4 * g4;
        float w0 = p[0], w1 = p[1], w2 = p[2], w3 = p[3];
        float w4 = p[4], w5 = p[5], w6 = p[6], w7 = p[7];
        float o0 = ((w0 + w1) + (w2 + w3)) + ((w4 + w5) + (w6 + w7));
        float w8 = p[8], w9 = p[9], w10 = p[10];
        float o1 = o0 - w0 + w8;
        float o2 = o1 - w1 + w9;
        float o3 = o2 - w2 + w10;
        int oxg = ox0 + 4 * g4;
        float* po = outn + (size_t)(b * OH + oy) * OW + oxg;
        if (oxg + 3 < OW) {
            po[0] = o0 * (1.0f / 64.0f);
            po[1] = o1 * (1.0f / 64.0f);
            po[2] = o2 * (1.0f / 64.0f);
            po[3] = o3 * (1.0f / 64.0f);
        } else {
            if (oxg     < OW) po[0] = o0 * (1.0f / 64.0f);
            if (oxg + 1 < OW) po[1] = o1 * (1.0f / 64.0f);
            if (oxg + 2 < OW) po[2] = o2 * (1.0f / 64.0f);
        }
    }
}

extern "C" void kernel_launch(void* const* d_in, const int* in_sizes, int n_in,
                              void* d_out, int out_size, void* d_ws, size_t ws_size,
                              hipStream_t stream) {
    const float* x = (const float*)d_in[0];
    // d_in[1] is the fixed Sobel weight [2,1,3,3]; hard-coded in the kernel.
    float* out = (float*)d_out;
    dim3 grid((OW + TW - 1) / TW, (OH + TH - 1) / TH, 32);
    hog_fused<<<grid, dim3(256), 0, stream>>>(x, out);
}

// Round 9
// 171.722 us; speedup vs baseline: 1.7114x; 1.2172x over previous
//
#include <hip/hip_runtime.h>
#include <math.h>

#define NB 10
#define H 512
#define W 512
#define OH 507
#define OW 507
#define TW 32           // output tile width
#define TH 16           // output tile height
#define HC (TW + 7)     // 39 hist cols  (ox0-1 .. ox0+TW+6)
#define HR (TH + 7)     // 23 hist rows
#define IC (TW + 9)     // 41 input cols (ox0-2 .. ox0+TW+7)
#define IR (TH + 9)     // 25 input rows
#define BD 512          // threads per block: 4 blocks/CU -> 32 waves/CU (100%)

// numpy float32 remainder (np.mod): fmod then sign-fix, each op exact IEEE f32.
__device__ __forceinline__ float f32mod10(float a) {
    float r = fmodf(a, 10.0f);
    if (r < 0.0f) r = __fadd_rn(r, 10.0f);
    return r;
}

__global__ __launch_bounds__(BD, 8)
void hog_fused(const float* __restrict__ x, float* __restrict__ out) {
    __shared__ __align__(16) float xin[IR][IC];      // 1025 f; reused as buf0 later
    __shared__ __align__(16) float hist[NB][HR][HC]; // 8970 f
    // total 9995 f = 39,980 B -> 4 blocks/CU, 512 thr each = 2048 thr/CU

    const int tid = threadIdx.x;
    const int ox0 = blockIdx.x * TW;
    const int oy0 = blockIdx.y * TH;
    const int n   = blockIdx.z;
    const float* __restrict__ xp = x + (size_t)n * (H * W);

    // ---- zero hist (vectorized) ----
    float* hflat = &hist[0][0][0];
    {
        float4* h4 = (float4*)hflat;                 // 8970 = 2242*4 + 2
        for (int i = tid; i < 2242; i += BD) h4[i] = make_float4(0.f, 0.f, 0.f, 0.f);
        if (tid < 2) hflat[8968 + tid] = 0.0f;
    }

    // ---- load input tile with halo (zero padded outside image) ----
    float* xflat = &xin[0][0];
    for (int i = tid; i < IR * IC; i += BD) {
        int r = i / IC, c = i % IC;
        int gy = oy0 - 2 + r, gx = ox0 - 2 + c;
        float v = 0.0f;
        if (gy >= 0 && gy < H && gx >= 0 && gx < W) v = xp[gy * W + gx];
        xflat[i] = v;
    }
    __syncthreads();

    // ---- Sobel + phase + 2-bin scatter into LDS hist (round-6 proven) ----
    for (int p = tid; p < HR * HC; p += BD) {
        int hr = p / HC, hc = p % HC;
        int hy = oy0 - 1 + hr, hx = ox0 - 1 + hc;
        if (hy < 0 || hy >= H || hx < 0 || hx >= W) continue;  // pool pad: zero
        float a00 = xin[hr][hc],     a01 = xin[hr][hc + 1],     a02 = xin[hr][hc + 2];
        float a10 = xin[hr + 1][hc],                            a12 = xin[hr + 1][hc + 2];
        float a20 = xin[hr + 2][hc], a21 = xin[hr + 2][hc + 1], a22 = xin[hr + 2][hc + 2];

        // exact numpy-order f32 conv (no contraction) — proven in round 3
        float gxv = __fadd_rn(a00, -a02);
        gxv = __fadd_rn(gxv, __fmul_rn(2.0f, a10));
        gxv = __fadd_rn(gxv, -__fmul_rn(2.0f, a12));
        gxv = __fadd_rn(gxv, a20);
        gxv = __fadd_rn(gxv, -a22);
        float gyv = __fadd_rn(a00, __fmul_rn(2.0f, a01));
        gyv = __fadd_rn(gyv, a02);
        gyv = __fadd_rn(gyv, -a20);
        gyv = __fadd_rn(gyv, -__fmul_rn(2.0f, a21));
        gyv = __fadd_rn(gyv, -a22);

        float ay_ = fabsf(gxv), ax_ = fabsf(gyv);
        float hi = fmaxf(ax_, ay_), lo = fminf(ax_, ay_);
        if (hi == 0.0f) continue;            // atan2(0,0)=0 -> contributes 0
        float nrm = __builtin_amdgcn_sqrtf(
            __fadd_rn(__fmul_rn(gxv, gxv), __fmul_rn(gyv, gyv)));

        // fast f32 atan2(gxv, gyv) * 10/pi, divide-free
        bool exact = (hi < 1e-30f) || (hi > 1e30f);
        float pint = 0.0f;
        if (!exact) {
            float t  = lo * __builtin_amdgcn_rcpf(hi);
            bool red = t > 0.41421356f;
            float u  = red ? (t - 1.0f) * __builtin_amdgcn_rcpf(t + 1.0f) : t;
            float z  = u * u;
            float pl = ((8.05374449538e-2f * z - 1.38776856032e-1f) * z
                        + 1.99777106478e-1f) * z - 3.33329491539e-1f;
            float a  = fmaf(u * z, pl, u);
            if (red) a += 0.78539816339744831f;
            if (ay_ > ax_) a = 1.57079632679489662f - a;
            if (gyv < 0.0f) a = 3.14159265358979324f - a;
            float ph = (gxv < 0.0f) ? -a : a;
            pint = ph * 3.18309886183790672f;
            if (fabsf(pint - rintf(pint)) < 1e-4f) exact = true;
        }

        float b_v, t_v;
        int ib, it;
        if (exact) {
            // bit-exact round-3 chain (matches np f32 reference)
            float phf = (float)atan2((double)gxv, (double)gyv);
            float pe  = __fmul_rn(__fdiv_rn(phf, (float)3.14159265358979323846), 10.0f);
            float bfv = floorf(pe), tfv = ceilf(pe);
            float fm = f32mod10(pe), bm = f32mod10(bfv), tm = f32mod10(tfv);
            t_v = __fmul_rn(nrm, __fsub_rn(1.0f, __fsub_rn(tm, fm)));
            b_v = __fmul_rn(nrm, __fsub_rn(1.0f, __fsub_rn(fm, bm)));
            ib = (((int)bfv % NB) + NB) % NB;
            it = (((int)tfv % NB) + NB) % NB;
        } else {
            // pint in (-10,10), >=1e-4 from any integer. Wrap strips
            // (t-index 0, tm=0) occur exactly when ib==9.
            float bfv  = floorf(pint);
            float frac = pint - bfv;
            float fm   = (pint < 0.0f) ? pint + 10.0f : pint;
            b_v = nrm * (1.0f - frac);
            int bi = (int)bfv;
            ib = (bi < 0) ? bi + 10 : bi;
            if (ib == 9) { it = 0;      t_v = nrm * (1.0f + fm); }
            else         { it = ib + 1; t_v = nrm * frac; }
        }
        // single owner per (hr,hc): plain RMW (LDS atomics are SLOW — round 7)
        hist[ib][hr][hc] = __fadd_rn(hist[ib][hr][hc], b_v);
        hist[it][hr][hc] = __fadd_rn(hist[it][hr][hc], t_v);
    }
    __syncthreads();

    // ---- vertical 8-row sliding sum, IN PLACE (round-6 proven) ----
    float* buf0 = &xin[0][0];                          // [NB][HC] = 390 f
    for (int q = tid; q < NB * HC; q += BD) {
        int b = q / HC, hc = q % HC;
        float s = 0.0f;
        #pragma unroll
        for (int hr = 0; hr < 8; ++hr) s += hist[b][hr][hc];
        buf0[b * HC + hc] = s;
        #pragma unroll 4
        for (int i = 1; i < TH; ++i) {
            s += hist[b][i + 7][hc] - hist[b][i - 1][hc];
            hist[b][i - 1][hc] = s;                    // overwrite after last read
        }
    }
    __syncthreads();

    // ---- horizontal: sliding 8-sum, 4 outputs per unit (11 reads vs 32) ----
    // unit u: b = u>>7, i = (u>>3)&15, g4 = u&7 -> output cols ox0+4*g4 .. +3
    float* __restrict__ outn = out + (size_t)n * (NB * OH * OW);
    for (int u = tid; u < NB * TH * 8; u += BD) {
        int b  = u >> 7;
        int i  = (u >> 3) & 15;
        int g4 = u & 7;
        int oy = oy0 + i;
        if (oy >= OH) continue;
        const float* cs = (i == 0) ? (buf0 + b * HC) : &hist[b][i - 1][0];
        const float* p  = cs + 4 * g4;
        float w0 = p[0], w1 = p[1], w2 = p[2], w3 = p[3];
        float w4 = p[4], w5 = p[5], w6 = p[6], w7 = p[7];
        float o0 = ((w0 + w1) + (w2 + w3)) + ((w4 + w5) + (w6 + w7));
        float w8 = p[8], w9 = p[9], w10 = p[10];
        float o1 = o0 - w0 + w8;
        float o2 = o1 - w1 + w9;
        float o3 = o2 - w2 + w10;
        int oxg = ox0 + 4 * g4;
        float* po = outn + (size_t)(b * OH + oy) * OW + oxg;
        if (oxg + 3 < OW) {
            po[0] = o0 * (1.0f / 64.0f);
            po[1] = o1 * (1.0f / 64.0f);
            po[2] = o2 * (1.0f / 64.0f);
            po[3] = o3 * (1.0f / 64.0f);
        } else {
            if (oxg     < OW) po[0] = o0 * (1.0f / 64.0f);
            if (oxg + 1 < OW) po[1] = o1 * (1.0f / 64.0f);
            if (oxg + 2 < OW) po[2] = o2 * (1.0f / 64.0f);
        }
    }
}

extern "C" void kernel_launch(void* const* d_in, const int* in_sizes, int n_in,
                              void* d_out, int out_size, void* d_ws, size_t ws_size,
                              hipStream_t stream) {
    const float* x = (const float*)d_in[0];
    // d_in[1] is the fixed Sobel weight [2,1,3,3]; hard-coded in the kernel.
    float* out = (float*)d_out;
    dim3 grid((OW + TW - 1) / TW, (OH + TH - 1) / TH, 32);
    hog_fused<<<grid, dim3(BD), 0, stream>>>(x, out);
}